// Round 5
// baseline (163.938 us; speedup 1.0000x reference)
//
#include <hip/hip_runtime.h>
#include <stdint.h>

#define D_IN  256
#define D_OUT 128
#define NSEQ  4096
#define NB    16
#define NBLK  1024                      // 64-row tiles; 4 blocks/CU -> all 1024 co-resident
#define LDS_BYTES 34816                 // bufA(16K Y2) + bufB(16K Y3) + wsum(2K)

typedef __bf16 bf16x8 __attribute__((ext_vector_type(8)));
typedef float  f32x4  __attribute__((ext_vector_type(4)));

__device__ __forceinline__ unsigned short f2bf(float f) {
  __bf16 h = (__bf16)f;
  union { __bf16 h; unsigned short u; } c; c.h = h;
  return c.u;
}
__device__ __forceinline__ float bf2f(unsigned short u) {
  union { unsigned int u; float f; } a; a.u = ((unsigned int)u) << 16;
  return a.f;
}

// prep: Wa = Wp @ W1 (fp32 accum -> bf16, [n][k] layout), W2 transpose,
// be1 = bp @ W1 + b1, S zeroed (atomicAdd target). Folding Wp@W1 is exact
// math (ReLU is the only nonlinearity).
__global__ __launch_bounds__(256) void prep(
    const float* __restrict__ Wp, const float* __restrict__ W1, const float* __restrict__ W2,
    const float* __restrict__ bp, const float* __restrict__ b1,
    unsigned short* __restrict__ WaT, unsigned short* __restrict__ W2T,
    float* __restrict__ be1, float* __restrict__ S) {
  int b = blockIdx.x;
  if (b < 128) {
    __shared__ float wp[256];
    int k0 = b * 2;
    wp[threadIdx.x] = Wp[k0 * 128 + threadIdx.x];
    __syncthreads();
    int kk = threadIdx.x >> 7, n = threadIdx.x & 127;
    float s = 0.f;
#pragma unroll 16
    for (int j = 0; j < 128; ++j) s += wp[kk * 128 + j] * W1[j * 128 + n];
    WaT[n * 256 + (k0 + kk)] = f2bf(s);
  } else if (b < 192) {
    int t = (b - 128) * 256 + threadIdx.x;
    int k = t >> 7, n = t & 127;
    W2T[n * 128 + k] = f2bf(W2[t]);
  } else {
    if (threadIdx.x < 128) {
      int n = threadIdx.x;
      float s = b1[n];
#pragma unroll 16
      for (int j = 0; j < 128; ++j) s += bp[j] * W1[j * 128 + n];
      be1[n] = s;
    } else {
      int i = threadIdx.x - 128;
#pragma unroll
      for (int j = 0; j < 16; ++j) S[i * 16 + j] = 0.f;   // 16x128 floats
    }
  }
}

// Main: 1024 blocks x 64 rows, 4 blocks/CU (all co-resident, single round).
// SPLIT-ROWS: wave w owns rows [w*16, w*16+16) x all 128 cols.
//  - GEMM-A (K=256): A-frags loaded DIRECT from global X (8 consecutive fp32
//    of one row -> cvt bf16) -- no LDS staging, no staging barriers.
//  - Y2 = relu(.+be1) -> bufA (swizzled). Rows are wave-private, so GEMM-B
//    reads them back with NO barrier (lgkmcnt ordering within the wave).
//  - GEMM-B (K=128) from LDS; Y3 -> bufB; ONE barrier; coalesced copy-out.
//  - Col sums: per-wave partials -> wsum(LDS) -> one atomicAdd per col into
//    S[batch] (device-scope; replaces P + 32 MB of redundant finalize reads).
// LDS swizzle: (row,col) -> row*128 + ((col>>3 ^ (row&15))<<3) + (col&7).
// NOTE (R3): cross-XCD grid.sync costs ~100+ us at this grid size; split
// kernels + same-grid L2 locality beat any cooperative fusion here.
template <bool USE_WS>
__global__ __launch_bounds__(256, 4) void fused2(
    const float* __restrict__ X,
    const unsigned short* __restrict__ WaT,
    const unsigned short* __restrict__ W2T,
    const float* __restrict__ be1, const float* __restrict__ b2v,
    unsigned short* __restrict__ Y3, float* __restrict__ out, float* __restrict__ S) {
  extern __shared__ unsigned short smem[];
  unsigned short* bufA = smem;            // Y2: 64x128 bf16 swizzled
  unsigned short* bufB = smem + 8192;     // Y3: 64x128 bf16 swizzled
  float* wsum = (float*)(smem + 16384);   // 4 x 128 per-wave col sums

  const int tid  = threadIdx.x;
  const int lane = tid & 63;
  const int w    = tid >> 6;
  const int q    = lane >> 4;
  const int l16  = lane & 15;
  const int blk  = blockIdx.x;
  const int rowbase = blk * 64;
  const int myrow   = w * 16 + l16;       // tile-row this lane's A-frags use

  // per-ct biases (col = ct*16 + l16)
  float e[8], bb[8];
#pragma unroll
  for (int ct = 0; ct < 8; ++ct) {
    e[ct]  = be1[ct * 16 + l16];
    bb[ct] = b2v[ct * 16 + l16];
  }

  f32x4 acc[8];
#pragma unroll
  for (int ct = 0; ct < 8; ++ct) acc[ct] = (f32x4){0.f, 0.f, 0.f, 0.f};

  const float* xrow = X + (size_t)(rowbase + myrow) * D_IN;

  // ---- GEMM-A: K=256, A direct from global (fp32 -> bf16 in-reg) ----
#pragma unroll
  for (int ks = 0; ks < 8; ++ks) {
    float4 lo = *(const float4*)(xrow + ks * 32 + q * 8);
    float4 hi = *(const float4*)(xrow + ks * 32 + q * 8 + 4);
    bf16x8 a;
    a[0] = (__bf16)lo.x; a[1] = (__bf16)lo.y; a[2] = (__bf16)lo.z; a[3] = (__bf16)lo.w;
    a[4] = (__bf16)hi.x; a[5] = (__bf16)hi.y; a[6] = (__bf16)hi.z; a[7] = (__bf16)hi.w;
#pragma unroll
    for (int ct = 0; ct < 8; ++ct) {
      bf16x8 b = *(const bf16x8*)(WaT + (size_t)(ct * 16 + l16) * 256 + ks * 32 + q * 8);
      acc[ct] = __builtin_amdgcn_mfma_f32_16x16x32_bf16(a, b, acc[ct], 0, 0, 0);
    }
  }

  // ---- epilogue A: Y2 = relu(acc + be1) -> bufA (wave-private rows) ----
#pragma unroll
  for (int ct = 0; ct < 8; ++ct) {
    int col = ct * 16 + l16;
    int cb = (col >> 3) << 3, c7 = col & 7;
#pragma unroll
    for (int r = 0; r < 4; ++r) {
      int row = w * 16 + q * 4 + r;
      float v = acc[ct][r] + e[ct]; v = v > 0.f ? v : 0.f;
      bufA[row * 128 + ((cb ^ ((row & 15) << 3)) + c7)] = f2bf(v);
    }
  }
  // no barrier: GEMM-B reads only rows written by this same wave.

#pragma unroll
  for (int ct = 0; ct < 8; ++ct) acc[ct] = (f32x4){0.f, 0.f, 0.f, 0.f};

  // ---- GEMM-B: K=128, A from LDS (own rows), B from W2T ----
#pragma unroll
  for (int ks = 0; ks < 4; ++ks) {
    bf16x8 a = *(const bf16x8*)(bufA + myrow * 128 + (((4 * ks + q) ^ l16) << 3));
#pragma unroll
    for (int ct = 0; ct < 8; ++ct) {
      bf16x8 b = *(const bf16x8*)(W2T + (size_t)(ct * 16 + l16) * 128 + ks * 32 + q * 8);
      acc[ct] = __builtin_amdgcn_mfma_f32_16x16x32_bf16(a, b, acc[ct], 0, 0, 0);
    }
  }

  // ---- epilogue B: Y3 = acc + b2 -> bufB; per-wave col sums -> wsum ----
#pragma unroll
  for (int ct = 0; ct < 8; ++ct) {
    int col = ct * 16 + l16;
    int cb = (col >> 3) << 3, c7 = col & 7;
    float s = 0.f;
#pragma unroll
    for (int r = 0; r < 4; ++r) {
      int row = w * 16 + q * 4 + r;
      float v = acc[ct][r] + bb[ct];
      s += v;
      bufB[row * 128 + ((cb ^ ((row & 15) << 3)) + c7)] = f2bf(v);
    }
    s += __shfl_down(s, 16); s += __shfl_down(s, 32);
    if (lane < 16) wsum[w * 128 + col] = s;
  }
  __syncthreads();   // the ONLY barrier: bufB + wsum complete

  // ---- col sums: one atomicAdd per col into S[batch] ----
  if (tid < 128) {
    float s = wsum[tid] + wsum[128 + tid] + wsum[256 + tid] + wsum[384 + tid];
    atomicAdd(&S[(size_t)(blk >> 6) * 128 + tid], s);
  }

  // ---- copy-out tile ----
  if (USE_WS) {
#pragma unroll
    for (int it = 0; it < 4; ++it) {
      int i = tid + it * 256;
      int r = i >> 4, g = i & 15;
      *(uint4*)(Y3 + (size_t)(rowbase + r) * 128 + g * 8) =
          *(const uint4*)(bufB + r * 128 + ((g ^ (r & 15)) << 3));
    }
  } else {
#pragma unroll
    for (int it = 0; it < 8; ++it) {
      int i = tid + it * 256;
      int r = i >> 5, c4 = (i & 31) << 2;
      ushort4 u = *(const ushort4*)(bufB + r * 128 + ((((c4 >> 3) ^ (r & 15)) << 3) + (c4 & 7)));
      float4 v; v.x = bf2f(u.x); v.y = bf2f(u.y); v.z = bf2f(u.z); v.w = bf2f(u.w);
      *(float4*)(out + (size_t)(rowbase + r) * D_OUT + c4) = v;
    }
  }
}

// finalize (ws path): 1024 blocks x 64 rows; S is ready (8 KB, LLC-hot).
// out[row][d] = S[b][d] - Y3[row][d]. Same grid as fused2 so Y3 reads hit
// the XCD-local L2 that wrote them.
__global__ __launch_bounds__(256) void finalize_ws(
    float* __restrict__ out, const unsigned short* __restrict__ Y3, const float* __restrict__ S) {
  __shared__ float fs[128];
  const int tid  = threadIdx.x;
  const int row0 = blockIdx.x * 64;
  const int b    = row0 >> 12;
  if (tid < 128) fs[tid] = S[(size_t)b * 128 + tid];
  __syncthreads();

#pragma unroll
  for (int it = 0; it < 4; ++it) {
    int i = tid + it * 256;
    int r = i >> 4, g = (i & 15) * 8;
    size_t base = (size_t)(row0 + r) * 128 + g;
    uint4 u = *(const uint4*)(Y3 + base);
    float4 s0 = *(const float4*)(fs + g);
    float4 s1 = *(const float4*)(fs + g + 4);
    union { unsigned int uu; float f; } t;
    float4 o0, o1;
    t.uu = u.x << 16;          o0.x = s0.x - t.f;
    t.uu = u.x & 0xFFFF0000u;  o0.y = s0.y - t.f;
    t.uu = u.y << 16;          o0.z = s0.z - t.f;
    t.uu = u.y & 0xFFFF0000u;  o0.w = s0.w - t.f;
    t.uu = u.z << 16;          o1.x = s1.x - t.f;
    t.uu = u.z & 0xFFFF0000u;  o1.y = s1.y - t.f;
    t.uu = u.w << 16;          o1.z = s1.z - t.f;
    t.uu = u.w & 0xFFFF0000u;  o1.w = s1.w - t.f;
    *(float4*)(out + base) = o0;
    *(float4*)(out + base + 4) = o1;
  }
}

// fallback finalize: out[row][d] = S[b][d] - out[row][d], in place
__global__ __launch_bounds__(256) void finalize_ip(
    float* __restrict__ out, const float* __restrict__ S) {
  __shared__ float fs[128];
  const int tid  = threadIdx.x;
  const int row0 = blockIdx.x * 64;
  const int b    = row0 >> 12;
  if (tid < 128) fs[tid] = S[(size_t)b * 128 + tid];
  __syncthreads();

#pragma unroll
  for (int it = 0; it < 4; ++it) {
    int i = tid + it * 256;
    int r = i >> 4, g = (i & 15) * 8;
    size_t base = (size_t)(row0 + r) * 128 + g;
    float4 s0 = *(const float4*)(fs + g);
    float4 s1 = *(const float4*)(fs + g + 4);
    float4 y0 = *(const float4*)(out + base);
    float4 y1 = *(const float4*)(out + base + 4);
    float4 o0, o1;
    o0.x = s0.x - y0.x; o0.y = s0.y - y0.y; o0.z = s0.z - y0.z; o0.w = s0.w - y0.w;
    o1.x = s1.x - y1.x; o1.y = s1.y - y1.y; o1.z = s1.z - y1.z; o1.w = s1.w - y1.w;
    *(float4*)(out + base) = o0;
    *(float4*)(out + base + 4) = o1;
  }
}

extern "C" void kernel_launch(void* const* d_in, const int* in_sizes, int n_in,
                              void* d_out, int out_size, void* d_ws, size_t ws_size,
                              hipStream_t stream) {
  const float* X  = (const float*)d_in[0];
  const float* Wp = (const float*)d_in[1];
  const float* bp = (const float*)d_in[2];
  const float* W1 = (const float*)d_in[3];
  const float* b1 = (const float*)d_in[4];
  const float* W2 = (const float*)d_in[5];
  const float* b2 = (const float*)d_in[6];
  float* out = (float*)d_out;

  char* ws = (char*)d_ws;
  float* S            = (float*)ws;                               // 8 KB (16 x 128)
  float* be1          = (float*)(ws + 8192);                      // 4 KB (512 B used)
  unsigned short* WaT = (unsigned short*)(ws + 12288);            // 64 KB (256x128 bf16 [n][k])
  unsigned short* W2T = (unsigned short*)(ws + 12288 + 65536);    // 32 KB
  unsigned short* Y3  = (unsigned short*)(ws + 12288 + 65536 + 32768);  // 16 MB

  const size_t need = 12288 + 65536 + 32768 + (size_t)NB * NSEQ * D_OUT * 2;
  const bool use_ws = ws_size >= need;

  prep<<<193, 256, 0, stream>>>(Wp, W1, W2, bp, b1, WaT, W2T, be1, S);

  if (use_ws) {
    fused2<true><<<NBLK, 256, LDS_BYTES, stream>>>(X, WaT, W2T, be1, b2, Y3, out, S);
    finalize_ws<<<NBLK, 256, 0, stream>>>(out, Y3, S);
  } else {
    fused2<false><<<NBLK, 256, LDS_BYTES, stream>>>(X, WaT, W2T, be1, b2, Y3, out, S);
    finalize_ip<<<NBLK, 256, 0, stream>>>(out, S);
  }
}